// Round 1
// baseline (39.960 us; speedup 1.0000x reference)
//
#include <hip/hip_runtime.h>
#include <hip/hip_bf16.h>
#include <stdint.h>

#define Bdim 16
#define Ndim 256
#define Kdim 2048
#define Vdim 768
#define Mdim 4096  // B*N

typedef __attribute__((ext_vector_type(8))) short short8;
typedef __attribute__((ext_vector_type(4))) float f32x4;

struct alignas(8) bf16x4 { __hip_bfloat16 x, y, z, w; };

__device__ __forceinline__ void gld_lds16(const void* g, void* l) {
    __builtin_amdgcn_global_load_lds((const __attribute__((address_space(1))) void*)g,
                                     (__attribute__((address_space(3))) void*)l, 16, 0, 0);
}

// One wave per row: fp32 -> bf16 convert + fp32 row sum-of-squares.
// 256 threads = 4 waves = 4 rows per block. Vdim=768 = 3 * 256 floats.
__global__ __launch_bounds__(256) void rowconv(const float* __restrict__ in,
                                               __hip_bfloat16* __restrict__ outb,
                                               float* __restrict__ sq) {
    const int row = blockIdx.x * 4 + (threadIdx.x >> 6);
    const int lane = threadIdx.x & 63;
    const float* rp = in + (size_t)row * Vdim;
    __hip_bfloat16* op = outb + (size_t)row * Vdim;
    float s = 0.f;
#pragma unroll
    for (int j = 0; j < Vdim / 256; ++j) {
        float4 v = *reinterpret_cast<const float4*>(rp + j * 256 + lane * 4);
        s += v.x * v.x + v.y * v.y + v.z * v.z + v.w * v.w;
        bf16x4 b;
        b.x = __float2bfloat16(v.x); b.y = __float2bfloat16(v.y);
        b.z = __float2bfloat16(v.z); b.w = __float2bfloat16(v.w);
        *reinterpret_cast<bf16x4*>(op + j * 256 + lane * 4) = b;
    }
#pragma unroll
    for (int off = 32; off > 0; off >>= 1) s += __shfl_down(s, off);
    if (lane == 0) sq[row] = s;
}

// m97-structure GEMM: C[m,n] = sum_v A[m,v]*P[n,v], fused distance epilogue.
// 128x128 tile, BK=32, 4 waves (2x2), 64x64 per wave, 16x16x32 bf16 MFMA.
__global__ __launch_bounds__(256) void gemm_dist(const __hip_bfloat16* __restrict__ Ab,
                                                 const __hip_bfloat16* __restrict__ Pb,
                                                 const float* __restrict__ xsq,
                                                 const float* __restrict__ psq,
                                                 float* __restrict__ out) {
    __shared__ __hip_bfloat16 As[128 * 32];
    __shared__ __hip_bfloat16 Bs[128 * 32];

    const int t = threadIdx.x;
    const int wave = t >> 6, lane = t & 63;
    const int wr = wave >> 1, wc = wave & 1;

    const int bm = blockIdx.x & 31;   // 32 M-tiles
    const int bn = blockIdx.x >> 5;   // 16 N-tiles
    const int m0 = bm * 128, n0 = bn * 128;

    const int srow = lane >> 2;        // staging: row within a 16-row slab
    const int scol = (lane & 3) * 8;   // staging: col (elements)

    const int fr = lane & 15;          // fragment row/col index
    const int fk = (lane >> 4) * 8;    // fragment k offset (elements)

    f32x4 acc[4][4] = {};

    for (int kt = 0; kt < Vdim / 32; ++kt) {
        const int v0 = kt * 32;
        // Stage A-tile (128x32) and B-tile (128x32): per matrix, 2 issues of
        // (4 waves x 16 rows); wave-uniform LDS base + lane*16B is row-major.
        gld_lds16(Ab + (size_t)(m0 + wave * 16 + srow) * Vdim + v0 + scol,
                  As + (wave * 16) * 32);
        gld_lds16(Ab + (size_t)(m0 + 64 + wave * 16 + srow) * Vdim + v0 + scol,
                  As + (64 + wave * 16) * 32);
        gld_lds16(Pb + (size_t)(n0 + wave * 16 + srow) * Vdim + v0 + scol,
                  Bs + (wave * 16) * 32);
        gld_lds16(Pb + (size_t)(n0 + 64 + wave * 16 + srow) * Vdim + v0 + scol,
                  Bs + (64 + wave * 16) * 32);
        __syncthreads();  // drains vmcnt before barrier

        short8 af[4], bf[4];
#pragma unroll
        for (int i = 0; i < 4; ++i) {
            af[i] = *reinterpret_cast<const short8*>(As + (wr * 64 + i * 16 + fr) * 32 + fk);
            bf[i] = *reinterpret_cast<const short8*>(Bs + (wc * 64 + i * 16 + fr) * 32 + fk);
        }
#pragma unroll
        for (int i = 0; i < 4; ++i)
#pragma unroll
            for (int j = 0; j < 4; ++j)
                acc[i][j] = __builtin_amdgcn_mfma_f32_16x16x32_bf16(af[i], bf[j], acc[i][j], 0, 0, 0);
        __syncthreads();
    }

    // Epilogue: dist = xsq[m] + psq[n] - 2*xp. C/D layout: col=lane&15,
    // row=(lane>>4)*4+reg (m89/m91-verified).
    const int fq = lane >> 4;
    float ps[4];
#pragma unroll
    for (int j = 0; j < 4; ++j) ps[j] = psq[n0 + wc * 64 + j * 16 + fr];
#pragma unroll
    for (int i = 0; i < 4; ++i) {
#pragma unroll
        for (int r = 0; r < 4; ++r) {
            const int m = m0 + wr * 64 + i * 16 + fq * 4 + r;
            const float xs = xsq[m];
            float* orow = out + (size_t)m * Kdim + n0 + wc * 64;
#pragma unroll
            for (int j = 0; j < 4; ++j)
                orow[j * 16 + fr] = xs + ps[j] - 2.0f * acc[i][j][r];
        }
    }
}

extern "C" void kernel_launch(void* const* d_in, const int* in_sizes, int n_in,
                              void* d_out, int out_size, void* d_ws, size_t ws_size,
                              hipStream_t stream) {
    const float* x = (const float*)d_in[0];   // (16,256,768) fp32
    const float* p = (const float*)d_in[1];   // (2048,768) fp32
    float* out = (float*)d_out;               // distances (4096x2048) + prototypes (2048x768)

    char* ws = (char*)d_ws;
    __hip_bfloat16* Ab = (__hip_bfloat16*)ws;                        // 6,291,456 B
    __hip_bfloat16* Pb = (__hip_bfloat16*)(ws + 6291456);            // 3,145,728 B
    float* xsq = (float*)(ws + 6291456 + 3145728);                   // 16,384 B
    float* psq = (float*)(ws + 6291456 + 3145728 + 16384);           // 8,192 B

    rowconv<<<Mdim / 4, 256, 0, stream>>>(x, Ab, xsq);
    rowconv<<<Kdim / 4, 256, 0, stream>>>(p, Pb, psq);
    gemm_dist<<<(Mdim / 128) * (Kdim / 128), 256, 0, stream>>>(Ab, Pb, xsq, psq, out);
    // Tuple output tail: prototypes passed through unchanged.
    hipMemcpyAsync(out + (size_t)Mdim * Kdim, p, (size_t)Kdim * Vdim * sizeof(float),
                   hipMemcpyDeviceToDevice, stream);
}

// Round 2
// 32.363 us; speedup vs baseline: 1.2347x; 1.2347x over previous
//
#include <hip/hip_runtime.h>
#include <hip/hip_bf16.h>
#include <stdint.h>

#define Bdim 16
#define Ndim 256
#define Kdim 2048
#define Vdim 768
#define Mdim 4096  // B*N

typedef __attribute__((ext_vector_type(8))) short short8;
typedef __attribute__((ext_vector_type(4))) float f32x4;

struct alignas(8) bf16x4 { __hip_bfloat16 x, y, z, w; };

__device__ __forceinline__ void gld_lds16(const void* g, void* l) {
    __builtin_amdgcn_global_load_lds((const __attribute__((address_space(1))) void*)g,
                                     (__attribute__((address_space(3))) void*)l, 16, 0, 0);
}

// Fused pre-pass, one wave per row (4 rows/block):
//   rows [0, Mdim)           : inputs  -> bf16 Ab + fp32 row sumsq xsq
//   rows [Mdim, Mdim+Kdim)   : protos  -> bf16 Pb + fp32 row sumsq psq
//                              + fp32 pass-through copy into out tail
__global__ __launch_bounds__(256) void rowconv_all(const float* __restrict__ x,
                                                   const float* __restrict__ p,
                                                   __hip_bfloat16* __restrict__ Ab,
                                                   __hip_bfloat16* __restrict__ Pb,
                                                   float* __restrict__ xsq,
                                                   float* __restrict__ psq,
                                                   float* __restrict__ proto_out) {
    const int row = blockIdx.x * 4 + (threadIdx.x >> 6);
    const int lane = threadIdx.x & 63;

    const float* src;
    __hip_bfloat16* dstb;
    float* sq;
    float* cpy = nullptr;
    if (row < Mdim) {
        src = x + (size_t)row * Vdim;
        dstb = Ab + (size_t)row * Vdim;
        sq = xsq + row;
    } else {
        const int r = row - Mdim;
        src = p + (size_t)r * Vdim;
        dstb = Pb + (size_t)r * Vdim;
        sq = psq + r;
        cpy = proto_out + (size_t)r * Vdim;
    }

    float s = 0.f;
#pragma unroll
    for (int j = 0; j < Vdim / 256; ++j) {
        float4 v = *reinterpret_cast<const float4*>(src + j * 256 + lane * 4);
        s += v.x * v.x + v.y * v.y + v.z * v.z + v.w * v.w;
        bf16x4 b;
        b.x = __float2bfloat16(v.x); b.y = __float2bfloat16(v.y);
        b.z = __float2bfloat16(v.z); b.w = __float2bfloat16(v.w);
        *reinterpret_cast<bf16x4*>(dstb + j * 256 + lane * 4) = b;
        if (cpy) *reinterpret_cast<float4*>(cpy + j * 256 + lane * 4) = v;
    }
#pragma unroll
    for (int off = 32; off > 0; off >>= 1) s += __shfl_down(s, off);
    if (lane == 0) *sq = s;
}

// 128x128 tile, BK=64 (2 k-slices of 32), double-buffered LDS, one barrier
// per K-step, next-tile global_load_lds issued before current-tile compute.
// 4 waves (2x2), 64x64 per wave, mfma_f32_16x16x32_bf16.
__global__ __launch_bounds__(256) void gemm_dist(const __hip_bfloat16* __restrict__ Ab,
                                                 const __hip_bfloat16* __restrict__ Pb,
                                                 const float* __restrict__ xsq,
                                                 const float* __restrict__ psq,
                                                 float* __restrict__ out) {
    // [buf][slice][row][col32]  -- slice keeps the 64B row stride of m97
    __shared__ __hip_bfloat16 As[2][2][128][32];
    __shared__ __hip_bfloat16 Bs[2][2][128][32];

    const int t = threadIdx.x;
    const int wave = t >> 6, lane = t & 63;
    const int wr = wave >> 1, wc = wave & 1;

    const int bm = blockIdx.x & 31;   // 32 M-tiles
    const int bn = blockIdx.x >> 5;   // 16 N-tiles
    const int m0 = bm * 128, n0 = bn * 128;

    const int sr = lane >> 2;         // staging row within a 16-row group
    const int sc = (lane & 3) * 8;    // staging col (elements, within 32)

    const int fr = lane & 15;         // fragment row index
    const int fk = (lane >> 4) * 8;   // fragment k offset (elements)

    f32x4 acc[4][4] = {};

    // Stage one BK=64 tile (A+B) into buffer `buf` from global k-offset v0.
    // Each issue: 256 threads x 16B = 4KB; lane->LDS mapping is linear
    // (lane*16B == row-major [16][64B]).
    auto stage = [&](int buf, int v0) {
#pragma unroll
        for (int j = 0; j < 4; ++j) {
            const int slice = j >> 1;
            const int rbase = (j & 1) * 64 + wave * 16;
            gld_lds16(Ab + (size_t)(m0 + rbase + sr) * Vdim + v0 + slice * 32 + sc,
                      &As[buf][slice][rbase][0]);
            gld_lds16(Pb + (size_t)(n0 + rbase + sr) * Vdim + v0 + slice * 32 + sc,
                      &Bs[buf][slice][rbase][0]);
        }
    };

    stage(0, 0);
    __syncthreads();

    int cur = 0;
    for (int kt = 0; kt < Vdim / 64; ++kt) {   // 12 iterations
        if (kt < Vdim / 64 - 1) stage(cur ^ 1, (kt + 1) * 64);

        short8 af[4][2], bg[4][2];
#pragma unroll
        for (int i = 0; i < 4; ++i)
#pragma unroll
            for (int s = 0; s < 2; ++s) {
                af[i][s] = *reinterpret_cast<const short8*>(&As[cur][s][wr * 64 + i * 16 + fr][fk]);
                bg[i][s] = *reinterpret_cast<const short8*>(&Bs[cur][s][wc * 64 + i * 16 + fr][fk]);
            }
#pragma unroll
        for (int s = 0; s < 2; ++s)
#pragma unroll
            for (int i = 0; i < 4; ++i)
#pragma unroll
                for (int j = 0; j < 4; ++j)
                    acc[i][j] = __builtin_amdgcn_mfma_f32_16x16x32_bf16(af[i][s], bg[j][s], acc[i][j], 0, 0, 0);

        __syncthreads();   // drains vmcnt (prefetch) + lgkmcnt; 1 barrier/iter
        cur ^= 1;
    }

    // Epilogue: dist = xsq[m] + psq[n] - 2*xp. C/D: col=lane&15, row=(lane>>4)*4+reg.
    const int fq = lane >> 4;
    float ps[4];
#pragma unroll
    for (int j = 0; j < 4; ++j) ps[j] = psq[n0 + wc * 64 + j * 16 + fr];
#pragma unroll
    for (int i = 0; i < 4; ++i) {
#pragma unroll
        for (int r = 0; r < 4; ++r) {
            const int m = m0 + wr * 64 + i * 16 + fq * 4 + r;
            const float xs = xsq[m];
            float* orow = out + (size_t)m * Kdim + n0 + wc * 64;
#pragma unroll
            for (int j = 0; j < 4; ++j)
                orow[j * 16 + fr] = xs + ps[j] - 2.0f * acc[i][j][r];
        }
    }
}

extern "C" void kernel_launch(void* const* d_in, const int* in_sizes, int n_in,
                              void* d_out, int out_size, void* d_ws, size_t ws_size,
                              hipStream_t stream) {
    const float* x = (const float*)d_in[0];   // (16,256,768) fp32
    const float* p = (const float*)d_in[1];   // (2048,768) fp32
    float* out = (float*)d_out;               // distances (4096x2048) + prototypes (2048x768)

    char* ws = (char*)d_ws;
    __hip_bfloat16* Ab = (__hip_bfloat16*)ws;                        // 6,291,456 B
    __hip_bfloat16* Pb = (__hip_bfloat16*)(ws + 6291456);            // 3,145,728 B
    float* xsq = (float*)(ws + 6291456 + 3145728);                   // 16,384 B
    float* psq = (float*)(ws + 6291456 + 3145728 + 16384);           // 8,192 B

    rowconv_all<<<(Mdim + Kdim) / 4, 256, 0, stream>>>(x, p, Ab, Pb, xsq, psq,
                                                       out + (size_t)Mdim * Kdim);
    gemm_dist<<<(Mdim / 128) * (Kdim / 128), 256, 0, stream>>>(Ab, Pb, xsq, psq, out);
}